// Round 5
// baseline (134.616 us; speedup 1.0000x reference)
//
#include <hip/hip_runtime.h>

#define NN 40000
#define NE 640000
#define D 128
#define CAP 64  // bucket capacity; P(Poisson(16) >= 64) ~ 3e-22

typedef __attribute__((ext_vector_type(8))) short short8;
typedef __attribute__((ext_vector_type(4))) float f32x4;
typedef __attribute__((ext_vector_type(4))) int i32x4;

__device__ __forceinline__ short f2b(float v) {
  unsigned int u = __builtin_bit_cast(unsigned int, v);
  u = (u + 0x7fffu + ((u >> 16) & 1u)) >> 16;
  return (short)u;
}
__device__ __forceinline__ float b2f(short s) {
  unsigned int u = ((unsigned int)(unsigned short)s) << 16;
  return __builtin_bit_cast(float, u);
}

// ---------------- K0: weights (bf16 transpose + Wg hi/lo split), zero cnt --
__global__ __launch_bounds__(256) void k_prep(
    const float* __restrict__ Wn, const float* __restrict__ Wg,
    const float* __restrict__ Wa, short* __restrict__ WnT,
    short* __restrict__ WgThi, short* __restrict__ WgTlo,
    short* __restrict__ WaT, int* __restrict__ cnt) {
  int i = blockIdx.x * 256 + threadIdx.x;  // 0..16383
  int k = i >> 7, c = i & 127;
  WnT[c * D + k] = f2b(Wn[k * D + c]);
  WaT[c * D + k] = f2b(Wa[k * D + c]);
  float v = Wg[k * D + c];
  short hi = f2b(v);
  WgThi[c * D + k] = hi;
  WgTlo[c * D + k] = f2b(v - b2f(hi));
  if (i < 10000) {  // zero cnt: 40000 ints = 10000 int4
    i32x4 z = {0, 0, 0, 0};
    *(i32x4*)(cnt + i * 4) = z;
  }
}

// ---------------- K1: node transform + edge bucket fill (block-split) ------
// Blocks [0,2500): 16 rows each -> h = x*sigmoid(x@Wa+ba) (bf16), xbf (bf16).
// Blocks [2500,5000): 256 edges each -> bucket fill via cnt atomics.
// A-frag: lane l holds row (l&15), k = kt*32 + (l>>4)*8 + j
// B-frag: lane l holds col (l&15), same k slots -> permutation-safe.
// C/D: col = lane&15, row = (lane>>4)*4 + reg
__global__ __launch_bounds__(256) void k_nf(
    const float* __restrict__ x, const short* __restrict__ WaT,
    const float* __restrict__ ba, short* __restrict__ h_out,
    short* __restrict__ xbf_out, const int* __restrict__ ei,
    int* __restrict__ cnt, int* __restrict__ bucket) {
  int bid = blockIdx.x;
  if (bid >= 2500) {
    int e = (bid - 2500) * 256 + threadIdx.x;  // 2500*256 == NE exactly
    int r = ei[e];       // destination row
    int c = ei[NE + e];  // source col
    int slot = atomicAdd(&cnt[r], 1);
    if (slot < CAP) bucket[r * CAP + slot] = c;
    return;
  }
  int r0 = bid * 16;
  int w = threadIdx.x >> 6, l = threadIdx.x & 63;
  int g = l >> 4, c16 = l & 15;
  int rowA = r0 + c16;

  short8 a[4];
#pragma unroll
  for (int kt = 0; kt < 4; ++kt) {
    const float* p = x + (size_t)rowA * D + kt * 32 + g * 8;
    f32x4 v0 = *(const f32x4*)p;
    f32x4 v1 = *(const f32x4*)(p + 4);
    short8 t;
    t[0] = f2b(v0[0]); t[1] = f2b(v0[1]); t[2] = f2b(v0[2]); t[3] = f2b(v0[3]);
    t[4] = f2b(v1[0]); t[5] = f2b(v1[1]); t[6] = f2b(v1[2]); t[7] = f2b(v1[3]);
    a[kt] = t;
    *(short8*)(xbf_out + (size_t)rowA * D + kt * 32 + g * 8) = t;
  }

#pragma unroll
  for (int u = 0; u < 2; ++u) {
    int ct = w * 2 + u;
    int cc = ct * 16 + c16;
    f32x4 c = {0.f, 0.f, 0.f, 0.f};
#pragma unroll
    for (int kt = 0; kt < 4; ++kt) {
      short8 b = *(const short8*)(WaT + (size_t)cc * D + kt * 32 + g * 8);
      c = __builtin_amdgcn_mfma_f32_16x16x32_bf16(a[kt], b, c, 0, 0, 0);
    }
    float bav = ba[cc];
#pragma unroll
    for (int r = 0; r < 4; ++r) {
      int rr = r0 + g * 4 + r;
      float t = c[r] + bav;
      float al = 1.0f / (1.0f + __expf(-t));
      float xv = x[(size_t)rr * D + cc];
      h_out[(size_t)rr * D + cc] = f2b(xv * al);
    }
  }
}

// ---------------- K2: fused aggregate (LDS s-tile) + output GEMM ----------
// Block = 16 nodes. Phase A: wave w aggregates nodes base+4w..+3 (MLP-8
// gather, shfl_xor group reduce) into LDS st[16][132] (pad -> <=2-way bank).
// Phase B: out = tanh(xbf@Wn + s@Wg(split hi/lo) + bn + bg) for the tile.
__global__ __launch_bounds__(256) void k_fused(
    const int* __restrict__ cnt, const int* __restrict__ bucket,
    const short* __restrict__ h, const short* __restrict__ xbf,
    const short* __restrict__ WnT, const short* __restrict__ WgThi,
    const short* __restrict__ WgTlo, const float* __restrict__ bn,
    const float* __restrict__ bg, float* __restrict__ out) {
  __shared__ float st[16][132];
  int w = threadIdx.x >> 6, l = threadIdx.x & 63;
  int g = l >> 4, i = l & 15;
  int base = blockIdx.x * 16;

  // ---- Phase A: aggregate 4 nodes per wave ----
#pragma unroll
  for (int v = 0; v < 4; ++v) {
    int n = base + w * 4 + v;
    int deg = cnt[n];
    deg = deg < CAP ? deg : CAP;
    int bc = bucket[(size_t)n * CAP + l];
    float acc[8];
#pragma unroll
    for (int q = 0; q < 8; ++q) acc[q] = 0.f;

    int j = 0;
    for (; j + 8 <= deg; j += 8) {
      int c0 = __shfl(bc, j + g);
      int c1 = __shfl(bc, j + 4 + g);
      short8 v0 = *(const short8*)(h + (size_t)c0 * D + i * 8);
      short8 v1 = *(const short8*)(h + (size_t)c1 * D + i * 8);
#pragma unroll
      for (int q = 0; q < 8; ++q) acc[q] += b2f(v0[q]);
#pragma unroll
      for (int q = 0; q < 8; ++q) acc[q] += b2f(v1[q]);
    }
    for (; j < deg; j += 4) {
      int src = j + g;
      int clamped = src < deg ? src : deg - 1;
      int c0 = __shfl(bc, clamped);
      if (src < deg) {
        short8 v0 = *(const short8*)(h + (size_t)c0 * D + i * 8);
#pragma unroll
        for (int q = 0; q < 8; ++q) acc[q] += b2f(v0[q]);
      }
    }
#pragma unroll
    for (int q = 0; q < 8; ++q) {
      acc[q] += __shfl_xor(acc[q], 16);
      acc[q] += __shfl_xor(acc[q], 32);
    }
    if (g == 0) {
      f32x4 lo = {acc[0], acc[1], acc[2], acc[3]};
      f32x4 hi = {acc[4], acc[5], acc[6], acc[7]};
      *(f32x4*)&st[w * 4 + v][i * 8] = lo;
      *(f32x4*)&st[w * 4 + v][i * 8 + 4] = hi;
    }
  }
  __syncthreads();

  // ---- Phase B: tile GEMM ----
  short8 axf[4], ash[4], asl[4];
  int rowG = base + i;
#pragma unroll
  for (int kt = 0; kt < 4; ++kt) {
    axf[kt] = *(const short8*)(xbf + (size_t)rowG * D + kt * 32 + g * 8);
    const float* p = &st[i][kt * 32 + g * 8];
    f32x4 v0 = *(const f32x4*)p;
    f32x4 v1 = *(const f32x4*)(p + 4);
    short8 hi, lo;
#pragma unroll
    for (int jq = 0; jq < 4; ++jq) {
      short hh = f2b(v0[jq]);
      hi[jq] = hh;
      lo[jq] = f2b(v0[jq] - b2f(hh));
    }
#pragma unroll
    for (int jq = 0; jq < 4; ++jq) {
      short hh = f2b(v1[jq]);
      hi[4 + jq] = hh;
      lo[4 + jq] = f2b(v1[jq] - b2f(hh));
    }
    ash[kt] = hi;
    asl[kt] = lo;
  }

#pragma unroll
  for (int u = 0; u < 2; ++u) {
    int ct = w * 2 + u;
    int cc = ct * 16 + i;
    f32x4 c = {0.f, 0.f, 0.f, 0.f};
#pragma unroll
    for (int kt = 0; kt < 4; ++kt) {
      short8 b = *(const short8*)(WnT + (size_t)cc * D + kt * 32 + g * 8);
      c = __builtin_amdgcn_mfma_f32_16x16x32_bf16(axf[kt], b, c, 0, 0, 0);
    }
#pragma unroll
    for (int kt = 0; kt < 4; ++kt) {
      short8 bh = *(const short8*)(WgThi + (size_t)cc * D + kt * 32 + g * 8);
      short8 bl = *(const short8*)(WgTlo + (size_t)cc * D + kt * 32 + g * 8);
      c = __builtin_amdgcn_mfma_f32_16x16x32_bf16(ash[kt], bh, c, 0, 0, 0);
      c = __builtin_amdgcn_mfma_f32_16x16x32_bf16(asl[kt], bh, c, 0, 0, 0);
      c = __builtin_amdgcn_mfma_f32_16x16x32_bf16(ash[kt], bl, c, 0, 0, 0);
    }
    float bias = bn[cc] + bg[cc];
#pragma unroll
    for (int r = 0; r < 4; ++r) {
      int rr = base + g * 4 + r;
      out[(size_t)rr * D + cc] = tanhf(c[r] + bias);
    }
  }
}

extern "C" void kernel_launch(void* const* d_in, const int* in_sizes, int n_in,
                              void* d_out, int out_size, void* d_ws,
                              size_t ws_size, hipStream_t stream) {
  const float* x = (const float*)d_in[0];
  const int* ei = (const int*)d_in[1];
  const float* Wn_w = (const float*)d_in[2];
  const float* Wn_b = (const float*)d_in[3];
  const float* Wg_w = (const float*)d_in[4];
  const float* Wg_b = (const float*)d_in[5];
  const float* Wa_w = (const float*)d_in[6];
  const float* Wa_b = (const float*)d_in[7];

  char* ws = (char*)d_ws;
  short* WaT = (short*)(ws + 0);
  short* WnT = (short*)(ws + 32 * 1024);
  short* WgThi = (short*)(ws + 64 * 1024);
  short* WgTlo = (short*)(ws + 96 * 1024);
  int* cnt = (int*)(ws + 128 * 1024);                          // 160 KB
  short* h = (short*)(ws + 512 * 1024);                        // 10.24 MB
  short* xbf = (short*)(ws + 512 * 1024 + (size_t)NN * D * 2); // 10.24 MB
  int* bucket = (int*)(ws + 512 * 1024 + (size_t)NN * D * 4);  // 10.24 MB
  float* out = (float*)d_out;

  k_prep<<<64, 256, 0, stream>>>(Wn_w, Wg_w, Wa_w, WnT, WgThi, WgTlo, WaT, cnt);
  k_nf<<<5000, 256, 0, stream>>>(x, WaT, Wa_b, h, xbf, ei, cnt, bucket);
  k_fused<<<2500, 256, 0, stream>>>(cnt, bucket, h, xbf, WnT, WgThi, WgTlo,
                                    Wn_b, Wg_b, out);
}

// Round 6
// 126.046 us; speedup vs baseline: 1.0680x; 1.0680x over previous
//
#include <hip/hip_runtime.h>

#define NN 40000
#define NE 640000
#define D 128
#define CAP 64  // bucket capacity; P(Poisson(16) >= 64) ~ 3e-22

typedef __attribute__((ext_vector_type(8))) short short8;
typedef __attribute__((ext_vector_type(4))) float f32x4;
typedef __attribute__((ext_vector_type(4))) int i32x4;

__device__ __forceinline__ short f2b(float v) {
  unsigned int u = __builtin_bit_cast(unsigned int, v);
  u = (u + 0x7fffu + ((u >> 16) & 1u)) >> 16;
  return (short)u;
}
__device__ __forceinline__ float b2f(short s) {
  unsigned int u = ((unsigned int)(unsigned short)s) << 16;
  return __builtin_bit_cast(float, u);
}

// ---------------- K0: weights (bf16 transpose + Wg hi/lo split), zero cnt --
__global__ __launch_bounds__(256) void k_prep(
    const float* __restrict__ Wn, const float* __restrict__ Wg,
    const float* __restrict__ Wa, short* __restrict__ WnT,
    short* __restrict__ WgThi, short* __restrict__ WgTlo,
    short* __restrict__ WaT, int* __restrict__ cnt) {
  int i = blockIdx.x * 256 + threadIdx.x;  // 0..16383
  int k = i >> 7, c = i & 127;
  WnT[c * D + k] = f2b(Wn[k * D + c]);
  WaT[c * D + k] = f2b(Wa[k * D + c]);
  float v = Wg[k * D + c];
  short hi = f2b(v);
  WgThi[c * D + k] = hi;
  WgTlo[c * D + k] = f2b(v - b2f(hi));
  if (i < 10000) {  // zero cnt: 40000 ints = 10000 int4
    i32x4 z = {0, 0, 0, 0};
    *(i32x4*)(cnt + i * 4) = z;
  }
}

// ---------------- K1: edge bucket fill ----------------
__global__ __launch_bounds__(256) void k_fill(
    const int* __restrict__ ei, int* __restrict__ cnt,
    int* __restrict__ bucket) {
  int e = blockIdx.x * 256 + threadIdx.x;
  if (e >= NE) return;
  int r = ei[e];       // destination row
  int c = ei[NE + e];  // source col
  int slot = atomicAdd(&cnt[r], 1);
  if (slot < CAP) bucket[r * CAP + slot] = c;
}

// ---------------- K2: node transform (16 rows/block) ----------------------
// A-frag: lane l holds row (l&15), k = kt*32 + (l>>4)*8 + j
// B-frag: lane l holds col (l&15), same k slots -> permutation-safe.
// C/D: col = lane&15, row = (lane>>4)*4 + reg
// alpha routed through LDS (C-layout write -> row-major read); h computed
// from f32 x kept in registers; vectorized short8 h stores (wave w owns kt=w).
__global__ __launch_bounds__(256) void k_node(
    const float* __restrict__ x, const short* __restrict__ WaT,
    const float* __restrict__ ba, short* __restrict__ h_out,
    short* __restrict__ xbf_out) {
  __shared__ float al_s[16][132];
  int r0 = blockIdx.x * 16;
  int w = threadIdx.x >> 6, l = threadIdx.x & 63;
  int g = l >> 4, c16 = l & 15;
  int rowA = r0 + c16;

  f32x4 xf[8];
  short8 a[4];
#pragma unroll
  for (int kt = 0; kt < 4; ++kt) {
    const float* p = x + (size_t)rowA * D + kt * 32 + g * 8;
    f32x4 v0 = *(const f32x4*)p;
    f32x4 v1 = *(const f32x4*)(p + 4);
    xf[kt * 2] = v0;
    xf[kt * 2 + 1] = v1;
    short8 t;
    t[0] = f2b(v0[0]); t[1] = f2b(v0[1]); t[2] = f2b(v0[2]); t[3] = f2b(v0[3]);
    t[4] = f2b(v1[0]); t[5] = f2b(v1[1]); t[6] = f2b(v1[2]); t[7] = f2b(v1[3]);
    a[kt] = t;
    *(short8*)(xbf_out + (size_t)rowA * D + kt * 32 + g * 8) = t;
  }

#pragma unroll
  for (int u = 0; u < 2; ++u) {
    int ct = w * 2 + u;
    int cc = ct * 16 + c16;
    f32x4 c = {0.f, 0.f, 0.f, 0.f};
#pragma unroll
    for (int kt = 0; kt < 4; ++kt) {
      short8 b = *(const short8*)(WaT + (size_t)cc * D + kt * 32 + g * 8);
      c = __builtin_amdgcn_mfma_f32_16x16x32_bf16(a[kt], b, c, 0, 0, 0);
    }
    float bav = ba[cc];
#pragma unroll
    for (int r = 0; r < 4; ++r) {
      float t = c[r] + bav;
      al_s[g * 4 + r][cc] = 1.0f / (1.0f + __expf(-t));
    }
  }
  __syncthreads();

  // wave w handles kt=w: h[rowA][w*32+g*8 .. +8] = x_f32 * alpha, bf16
  short8 hh;
#pragma unroll
  for (int q = 0; q < 8; ++q) {
    float av = al_s[c16][w * 32 + g * 8 + q];
    float xv = xf[w * 2 + (q >> 2)][q & 3];
    hh[q] = f2b(xv * av);
  }
  *(short8*)(h_out + (size_t)rowA * D + w * 32 + g * 8) = hh;
}

// ---------------- K3: fused aggregate (LDS s-tile) + output GEMM ----------
// Block = 16 nodes. Phase A: wave w aggregates nodes base+4w..+3 (MLP-8
// gather, shfl_xor group reduce) into LDS st[16][132].
// Phase B: out = tanh(xbf@Wn + s@Wg(split hi/lo) + bn + bg) for the tile.
__global__ __launch_bounds__(256) void k_fused(
    const int* __restrict__ cnt, const int* __restrict__ bucket,
    const short* __restrict__ h, const short* __restrict__ xbf,
    const short* __restrict__ WnT, const short* __restrict__ WgThi,
    const short* __restrict__ WgTlo, const float* __restrict__ bn,
    const float* __restrict__ bg, float* __restrict__ out) {
  __shared__ float st[16][132];
  int w = threadIdx.x >> 6, l = threadIdx.x & 63;
  int g = l >> 4, i = l & 15;
  int base = blockIdx.x * 16;

  // ---- Phase A: aggregate 4 nodes per wave ----
#pragma unroll
  for (int v = 0; v < 4; ++v) {
    int n = base + w * 4 + v;
    int deg = cnt[n];
    deg = deg < CAP ? deg : CAP;
    int bc = bucket[(size_t)n * CAP + l];
    float acc[8];
#pragma unroll
    for (int q = 0; q < 8; ++q) acc[q] = 0.f;

    int j = 0;
    for (; j + 8 <= deg; j += 8) {
      int c0 = __shfl(bc, j + g);
      int c1 = __shfl(bc, j + 4 + g);
      short8 v0 = *(const short8*)(h + (size_t)c0 * D + i * 8);
      short8 v1 = *(const short8*)(h + (size_t)c1 * D + i * 8);
#pragma unroll
      for (int q = 0; q < 8; ++q) acc[q] += b2f(v0[q]);
#pragma unroll
      for (int q = 0; q < 8; ++q) acc[q] += b2f(v1[q]);
    }
    for (; j < deg; j += 4) {
      int src = j + g;
      int clamped = src < deg ? src : deg - 1;
      int c0 = __shfl(bc, clamped);
      if (src < deg) {
        short8 v0 = *(const short8*)(h + (size_t)c0 * D + i * 8);
#pragma unroll
        for (int q = 0; q < 8; ++q) acc[q] += b2f(v0[q]);
      }
    }
#pragma unroll
    for (int q = 0; q < 8; ++q) {
      acc[q] += __shfl_xor(acc[q], 16);
      acc[q] += __shfl_xor(acc[q], 32);
    }
    if (g == 0) {
      f32x4 lo = {acc[0], acc[1], acc[2], acc[3]};
      f32x4 hi = {acc[4], acc[5], acc[6], acc[7]};
      *(f32x4*)&st[w * 4 + v][i * 8] = lo;
      *(f32x4*)&st[w * 4 + v][i * 8 + 4] = hi;
    }
  }
  __syncthreads();

  // ---- Phase B: tile GEMM ----
  short8 axf[4], ash[4], asl[4];
  int rowG = base + i;
#pragma unroll
  for (int kt = 0; kt < 4; ++kt) {
    axf[kt] = *(const short8*)(xbf + (size_t)rowG * D + kt * 32 + g * 8);
    const float* p = &st[i][kt * 32 + g * 8];
    f32x4 v0 = *(const f32x4*)p;
    f32x4 v1 = *(const f32x4*)(p + 4);
    short8 hi, lo;
#pragma unroll
    for (int jq = 0; jq < 4; ++jq) {
      short hh = f2b(v0[jq]);
      hi[jq] = hh;
      lo[jq] = f2b(v0[jq] - b2f(hh));
    }
#pragma unroll
    for (int jq = 0; jq < 4; ++jq) {
      short hh = f2b(v1[jq]);
      hi[4 + jq] = hh;
      lo[4 + jq] = f2b(v1[jq] - b2f(hh));
    }
    ash[kt] = hi;
    asl[kt] = lo;
  }

#pragma unroll
  for (int u = 0; u < 2; ++u) {
    int ct = w * 2 + u;
    int cc = ct * 16 + i;
    f32x4 c = {0.f, 0.f, 0.f, 0.f};
#pragma unroll
    for (int kt = 0; kt < 4; ++kt) {
      short8 b = *(const short8*)(WnT + (size_t)cc * D + kt * 32 + g * 8);
      c = __builtin_amdgcn_mfma_f32_16x16x32_bf16(axf[kt], b, c, 0, 0, 0);
    }
#pragma unroll
    for (int kt = 0; kt < 4; ++kt) {
      short8 bh = *(const short8*)(WgThi + (size_t)cc * D + kt * 32 + g * 8);
      short8 bl = *(const short8*)(WgTlo + (size_t)cc * D + kt * 32 + g * 8);
      c = __builtin_amdgcn_mfma_f32_16x16x32_bf16(ash[kt], bh, c, 0, 0, 0);
      c = __builtin_amdgcn_mfma_f32_16x16x32_bf16(asl[kt], bh, c, 0, 0, 0);
      c = __builtin_amdgcn_mfma_f32_16x16x32_bf16(ash[kt], bl, c, 0, 0, 0);
    }
    float bias = bn[cc] + bg[cc];
#pragma unroll
    for (int r = 0; r < 4; ++r) {
      int rr = base + g * 4 + r;
      out[(size_t)rr * D + cc] = tanhf(c[r] + bias);
    }
  }
}

extern "C" void kernel_launch(void* const* d_in, const int* in_sizes, int n_in,
                              void* d_out, int out_size, void* d_ws,
                              size_t ws_size, hipStream_t stream) {
  const float* x = (const float*)d_in[0];
  const int* ei = (const int*)d_in[1];
  const float* Wn_w = (const float*)d_in[2];
  const float* Wn_b = (const float*)d_in[3];
  const float* Wg_w = (const float*)d_in[4];
  const float* Wg_b = (const float*)d_in[5];
  const float* Wa_w = (const float*)d_in[6];
  const float* Wa_b = (const float*)d_in[7];

  char* ws = (char*)d_ws;
  short* WaT = (short*)(ws + 0);
  short* WnT = (short*)(ws + 32 * 1024);
  short* WgThi = (short*)(ws + 64 * 1024);
  short* WgTlo = (short*)(ws + 96 * 1024);
  int* cnt = (int*)(ws + 128 * 1024);                          // 160 KB
  short* h = (short*)(ws + 512 * 1024);                        // 10.24 MB
  short* xbf = (short*)(ws + 512 * 1024 + (size_t)NN * D * 2); // 10.24 MB
  int* bucket = (int*)(ws + 512 * 1024 + (size_t)NN * D * 4);  // 10.24 MB
  float* out = (float*)d_out;

  k_prep<<<64, 256, 0, stream>>>(Wn_w, Wg_w, Wa_w, WnT, WgThi, WgTlo, WaT, cnt);
  k_fill<<<(NE + 255) / 256, 256, 0, stream>>>(ei, cnt, bucket);
  k_node<<<NN / 16, 256, 0, stream>>>(x, WaT, Wa_b, h, xbf);
  k_fused<<<2500, 256, 0, stream>>>(cnt, bucket, h, xbf, WnT, WgThi, WgTlo,
                                    Wn_b, Wg_b, out);
}

// Round 7
// 122.454 us; speedup vs baseline: 1.0993x; 1.0293x over previous
//
#include <hip/hip_runtime.h>

#define NN 40000
#define NE 640000
#define D 128
#define CAP 64  // bucket capacity; P(Poisson(16) >= 64) ~ 3e-22

typedef __attribute__((ext_vector_type(8))) short short8;
typedef __attribute__((ext_vector_type(4))) float f32x4;
typedef __attribute__((ext_vector_type(4))) int i32x4;

__device__ __forceinline__ short f2b(float v) {
  unsigned int u = __builtin_bit_cast(unsigned int, v);
  u = (u + 0x7fffu + ((u >> 16) & 1u)) >> 16;
  return (short)u;
}
__device__ __forceinline__ float b2f(short s) {
  unsigned int u = ((unsigned int)(unsigned short)s) << 16;
  return __builtin_bit_cast(float, u);
}

// ---------------- K0: weights (bf16 transpose + Wg hi/lo split), zero cnt --
__global__ __launch_bounds__(256) void k_prep(
    const float* __restrict__ Wn, const float* __restrict__ Wg,
    const float* __restrict__ Wa, short* __restrict__ WnT,
    short* __restrict__ WgThi, short* __restrict__ WgTlo,
    short* __restrict__ WaT, int* __restrict__ cnt) {
  int i = blockIdx.x * 256 + threadIdx.x;  // 0..16383
  int k = i >> 7, c = i & 127;
  WnT[c * D + k] = f2b(Wn[k * D + c]);
  WaT[c * D + k] = f2b(Wa[k * D + c]);
  float v = Wg[k * D + c];
  short hi = f2b(v);
  WgThi[c * D + k] = hi;
  WgTlo[c * D + k] = f2b(v - b2f(hi));
  if (i < 10000) {  // zero cnt: 40000 ints = 10000 int4
    i32x4 z = {0, 0, 0, 0};
    *(i32x4*)(cnt + i * 4) = z;
  }
}

// ---------------- K1: edge bucket fill ----------------
__global__ __launch_bounds__(256) void k_fill(
    const int* __restrict__ ei, int* __restrict__ cnt,
    int* __restrict__ bucket) {
  int e = blockIdx.x * 256 + threadIdx.x;
  if (e >= NE) return;
  int r = ei[e];       // destination row
  int c = ei[NE + e];  // source col
  int slot = atomicAdd(&cnt[r], 1);
  if (slot < CAP) bucket[r * CAP + slot] = c;
}

// ---------------- K2: node transform (16 rows/block) ----------------------
// A-frag: lane l holds row (l&15), k = kt*32 + (l>>4)*8 + j
// B-frag: lane l holds col (l&15), same k slots -> permutation-safe.
// C/D: col = lane&15, row = (lane>>4)*4 + reg
__global__ __launch_bounds__(256) void k_node(
    const float* __restrict__ x, const short* __restrict__ WaT,
    const float* __restrict__ ba, short* __restrict__ h_out,
    short* __restrict__ xbf_out) {
  __shared__ float al_s[16][132];
  int r0 = blockIdx.x * 16;
  int w = threadIdx.x >> 6, l = threadIdx.x & 63;
  int g = l >> 4, c16 = l & 15;
  int rowA = r0 + c16;

  f32x4 xf[8];
  short8 a[4];
#pragma unroll
  for (int kt = 0; kt < 4; ++kt) {
    const float* p = x + (size_t)rowA * D + kt * 32 + g * 8;
    f32x4 v0 = *(const f32x4*)p;
    f32x4 v1 = *(const f32x4*)(p + 4);
    xf[kt * 2] = v0;
    xf[kt * 2 + 1] = v1;
    short8 t;
    t[0] = f2b(v0[0]); t[1] = f2b(v0[1]); t[2] = f2b(v0[2]); t[3] = f2b(v0[3]);
    t[4] = f2b(v1[0]); t[5] = f2b(v1[1]); t[6] = f2b(v1[2]); t[7] = f2b(v1[3]);
    a[kt] = t;
    *(short8*)(xbf_out + (size_t)rowA * D + kt * 32 + g * 8) = t;
  }

#pragma unroll
  for (int u = 0; u < 2; ++u) {
    int ct = w * 2 + u;
    int cc = ct * 16 + c16;
    f32x4 c = {0.f, 0.f, 0.f, 0.f};
#pragma unroll
    for (int kt = 0; kt < 4; ++kt) {
      short8 b = *(const short8*)(WaT + (size_t)cc * D + kt * 32 + g * 8);
      c = __builtin_amdgcn_mfma_f32_16x16x32_bf16(a[kt], b, c, 0, 0, 0);
    }
    float bav = ba[cc];
#pragma unroll
    for (int r = 0; r < 4; ++r) {
      float t = c[r] + bav;
      al_s[g * 4 + r][cc] = 1.0f / (1.0f + __expf(-t));
    }
  }
  __syncthreads();

  short8 hh;
#pragma unroll
  for (int q = 0; q < 8; ++q) {
    float av = al_s[c16][w * 32 + g * 8 + q];
    float xv = xf[w * 2 + (q >> 2)][q & 3];
    hh[q] = f2b(xv * av);
  }
  *(short8*)(h_out + (size_t)rowA * D + w * 32 + g * 8) = hh;
}

// ---------------- K3: fused aggregate + output GEMM (512 thr, 8 waves) ----
// Block = 16 nodes. Phase A: wave w aggregates node PAIR (base+2w, +1),
// interleaved -> 4 independent 16B loads per iteration. Phase B: ct = w.
__global__ __launch_bounds__(512) void k_fused(
    const int* __restrict__ cnt, const int* __restrict__ bucket,
    const short* __restrict__ h, const short* __restrict__ xbf,
    const short* __restrict__ WnT, const short* __restrict__ WgThi,
    const short* __restrict__ WgTlo, const float* __restrict__ bn,
    const float* __restrict__ bg, float* __restrict__ out) {
  __shared__ float st[16][132];
  int w = threadIdx.x >> 6, l = threadIdx.x & 63;
  int g = l >> 4, i = l & 15;
  int base = blockIdx.x * 16;

  // ---- Phase A: node pair per wave ----
  {
    int n0 = base + w * 2, n1 = n0 + 1;
    int deg0 = cnt[n0]; deg0 = deg0 < CAP ? deg0 : CAP;
    int deg1 = cnt[n1]; deg1 = deg1 < CAP ? deg1 : CAP;
    int bc0 = bucket[(size_t)n0 * CAP + l];
    int bc1 = bucket[(size_t)n1 * CAP + l];
    float a0[8], a1[8];
#pragma unroll
    for (int q = 0; q < 8; ++q) { a0[q] = 0.f; a1[q] = 0.f; }

    int dmin = (deg0 < deg1 ? deg0 : deg1) & ~7;
    int j = 0;
    for (; j < dmin; j += 8) {
      int c00 = __shfl(bc0, j + g);
      int c01 = __shfl(bc0, j + 4 + g);
      int c10 = __shfl(bc1, j + g);
      int c11 = __shfl(bc1, j + 4 + g);
      short8 v00 = *(const short8*)(h + (size_t)c00 * D + i * 8);
      short8 v01 = *(const short8*)(h + (size_t)c01 * D + i * 8);
      short8 v10 = *(const short8*)(h + (size_t)c10 * D + i * 8);
      short8 v11 = *(const short8*)(h + (size_t)c11 * D + i * 8);
#pragma unroll
      for (int q = 0; q < 8; ++q) {
        a0[q] += b2f(v00[q]); a0[q] += b2f(v01[q]);
        a1[q] += b2f(v10[q]); a1[q] += b2f(v11[q]);
      }
    }
    for (int t = j; t < deg0; t += 4) {
      int src = t + g;
      int cl = src < deg0 ? src : deg0 - 1;
      int c0 = __shfl(bc0, cl);
      if (src < deg0) {
        short8 v0 = *(const short8*)(h + (size_t)c0 * D + i * 8);
#pragma unroll
        for (int q = 0; q < 8; ++q) a0[q] += b2f(v0[q]);
      }
    }
    for (int t = j; t < deg1; t += 4) {
      int src = t + g;
      int cl = src < deg1 ? src : deg1 - 1;
      int c0 = __shfl(bc1, cl);
      if (src < deg1) {
        short8 v0 = *(const short8*)(h + (size_t)c0 * D + i * 8);
#pragma unroll
        for (int q = 0; q < 8; ++q) a1[q] += b2f(v0[q]);
      }
    }
#pragma unroll
    for (int q = 0; q < 8; ++q) {
      a0[q] += __shfl_xor(a0[q], 16);
      a0[q] += __shfl_xor(a0[q], 32);
      a1[q] += __shfl_xor(a1[q], 16);
      a1[q] += __shfl_xor(a1[q], 32);
    }
    if (g == 0) {
      f32x4 lo = {a0[0], a0[1], a0[2], a0[3]};
      f32x4 hi = {a0[4], a0[5], a0[6], a0[7]};
      *(f32x4*)&st[w * 2][i * 8] = lo;
      *(f32x4*)&st[w * 2][i * 8 + 4] = hi;
    } else if (g == 1) {
      f32x4 lo = {a1[0], a1[1], a1[2], a1[3]};
      f32x4 hi = {a1[4], a1[5], a1[6], a1[7]};
      *(f32x4*)&st[w * 2 + 1][i * 8] = lo;
      *(f32x4*)&st[w * 2 + 1][i * 8 + 4] = hi;
    }
  }
  __syncthreads();

  // ---- Phase B: wave w computes cols [w*16, w*16+16) ----
  int rowG = base + i;
  int cc = w * 16 + i;
  f32x4 c = {0.f, 0.f, 0.f, 0.f};
  float bias = bn[cc] + bg[cc];
#pragma unroll
  for (int kt = 0; kt < 4; ++kt) {
    // A-frags for this kt
    short8 axf = *(const short8*)(xbf + (size_t)rowG * D + kt * 32 + g * 8);
    const float* p = &st[i][kt * 32 + g * 8];
    f32x4 v0 = *(const f32x4*)p;
    f32x4 v1 = *(const f32x4*)(p + 4);
    short8 sh, sl;
#pragma unroll
    for (int jq = 0; jq < 4; ++jq) {
      short hh = f2b(v0[jq]);
      sh[jq] = hh;
      sl[jq] = f2b(v0[jq] - b2f(hh));
    }
#pragma unroll
    for (int jq = 0; jq < 4; ++jq) {
      short hh = f2b(v1[jq]);
      sh[4 + jq] = hh;
      sl[4 + jq] = f2b(v1[jq] - b2f(hh));
    }
    short8 bwn = *(const short8*)(WnT + (size_t)cc * D + kt * 32 + g * 8);
    short8 bh = *(const short8*)(WgThi + (size_t)cc * D + kt * 32 + g * 8);
    short8 bl = *(const short8*)(WgTlo + (size_t)cc * D + kt * 32 + g * 8);
    c = __builtin_amdgcn_mfma_f32_16x16x32_bf16(axf, bwn, c, 0, 0, 0);
    c = __builtin_amdgcn_mfma_f32_16x16x32_bf16(sh, bh, c, 0, 0, 0);
    c = __builtin_amdgcn_mfma_f32_16x16x32_bf16(sl, bh, c, 0, 0, 0);
    c = __builtin_amdgcn_mfma_f32_16x16x32_bf16(sh, bl, c, 0, 0, 0);
  }
#pragma unroll
  for (int r = 0; r < 4; ++r) {
    int rr = base + g * 4 + r;
    out[(size_t)rr * D + cc] = tanhf(c[r] + bias);
  }
}

extern "C" void kernel_launch(void* const* d_in, const int* in_sizes, int n_in,
                              void* d_out, int out_size, void* d_ws,
                              size_t ws_size, hipStream_t stream) {
  const float* x = (const float*)d_in[0];
  const int* ei = (const int*)d_in[1];
  const float* Wn_w = (const float*)d_in[2];
  const float* Wn_b = (const float*)d_in[3];
  const float* Wg_w = (const float*)d_in[4];
  const float* Wg_b = (const float*)d_in[5];
  const float* Wa_w = (const float*)d_in[6];
  const float* Wa_b = (const float*)d_in[7];

  char* ws = (char*)d_ws;
  short* WaT = (short*)(ws + 0);
  short* WnT = (short*)(ws + 32 * 1024);
  short* WgThi = (short*)(ws + 64 * 1024);
  short* WgTlo = (short*)(ws + 96 * 1024);
  int* cnt = (int*)(ws + 128 * 1024);                          // 160 KB
  short* h = (short*)(ws + 512 * 1024);                        // 10.24 MB
  short* xbf = (short*)(ws + 512 * 1024 + (size_t)NN * D * 2); // 10.24 MB
  int* bucket = (int*)(ws + 512 * 1024 + (size_t)NN * D * 4);  // 10.24 MB
  float* out = (float*)d_out;

  k_prep<<<64, 256, 0, stream>>>(Wn_w, Wg_w, Wa_w, WnT, WgThi, WgTlo, WaT, cnt);
  k_fill<<<(NE + 255) / 256, 256, 0, stream>>>(ei, cnt, bucket);
  k_node<<<NN / 16, 256, 0, stream>>>(x, WaT, Wa_b, h, xbf);
  k_fused<<<2500, 512, 0, stream>>>(cnt, bucket, h, xbf, WnT, WgThi, WgTlo,
                                    Wn_b, Wg_b, out);
}